// Round 4
// baseline (526.364 us; speedup 1.0000x reference)
//
#include <hip/hip_runtime.h>
#include <hip/hip_bf16.h>
#include <stdint.h>
#include <stddef.h>

#define Bn 4
#define Sn 2048
#define En 1024
#define Hn 16
#define DIn 64
#define BSn (Bn*Sn)   // 8192

typedef __attribute__((ext_vector_type(8))) short short8;
typedef __attribute__((ext_vector_type(4))) short short4v;
typedef __attribute__((ext_vector_type(4))) float fx4;
typedef __attribute__((ext_vector_type(16))) float fx16;
typedef __attribute__((ext_vector_type(8))) _Float16 half8;
typedef __attribute__((ext_vector_type(4))) _Float16 half4;
typedef __attribute__((ext_vector_type(4))) int ix4;

__device__ __forceinline__ short f2bf(float f){
  union U { __hip_bfloat16 h; short s; } u; u.h = __float2bfloat16(f); return u.s;
}
__device__ __forceinline__ int pk2(float a, float b){
  unsigned lo = (unsigned short)f2bf(a);
  unsigned hi = (unsigned short)f2bf(b);
  return (int)(lo | (hi << 16));
}

__device__ __forceinline__ void async16(const void* g, void* l){
  __builtin_amdgcn_global_load_lds((const __attribute__((address_space(1))) unsigned int*)g,
                                   (__attribute__((address_space(3))) unsigned int*)l, 16, 0, 0);
}

__device__ __forceinline__ fx4 mfma_bf(short8 a, short8 b, fx4 c){
  return __builtin_amdgcn_mfma_f32_16x16x32_bf16(a, b, c, 0, 0, 0);
}
__device__ __forceinline__ fx4 mfma_h(short8 a, short8 b, fx4 c){
  return __builtin_amdgcn_mfma_f32_16x16x32_f16(__builtin_bit_cast(half8, a),
                                                __builtin_bit_cast(half8, b), c, 0, 0, 0);
}
__device__ __forceinline__ fx16 mfma32(short8 a, short8 b, fx16 c){
  return __builtin_amdgcn_mfma_f32_32x32x16_bf16(a, b, c, 0, 0, 0);
}

// ---------------- cast f32 -> bf16 (vectorized x4) ----------------
__global__ void cast_bf16_k(const float* __restrict__ in, short* __restrict__ out, int n4){
  int i = blockIdx.x*256 + threadIdx.x;
  if (i >= n4) return;
  fx4 v = ((const fx4*)in)[i];
  short4v o = { f2bf(v[0]), f2bf(v[1]), f2bf(v[2]), f2bf(v[3]) };
  ((short4v*)out)[i] = o;
}

// ---------------- per-(b,s) row prep ----------------
// bias(q,k) = F_q . G_k ; a1v = 0.125*invT (logit = (qk + 8*bias)*a1)
__global__ void prep_rows_k(const float* __restrict__ mu, const float* __restrict__ sigma,
                            const float* __restrict__ assign, const float* __restrict__ explore,
                            const float* __restrict__ exploit, const int* __restrict__ mask,
                            _Float16* __restrict__ F, _Float16* __restrict__ G,
                            float* __restrict__ a1v){
  int r = blockIdx.x;          // 0..BSn-1
  int lane = threadIdx.x;      // 64
  float muv = mu[(size_t)r*DIn + lane];
  float sgv = sigma[(size_t)r*DIn + lane];
  float sq = muv*muv, sg = sgv;
  #pragma unroll
  for (int m=32; m; m>>=1){ sq += __shfl_xor(sq,m,64); sg += __shfl_xor(sg,m,64); }
  float unc = sg*(1.f/64.f);
  #pragma unroll
  for (int cb=0; cb<128; cb+=64){
    int col = cb + lane;
    float fv, gv;
    if (col < 32){ float a = assign[(size_t)r*32 + col]; fv = 0.5f*a; gv = a; }
    else if (col < 96){ float m2 = mu[(size_t)r*DIn + (col-32)]; fv = m2*(1.f/64.f); gv = m2; }
    else if (col == 96){ fv = -sq*(1.f/128.f); gv = 1.f; }
    else if (col == 97){ fv = 1.f; gv = -(sq*(1.f/128.f) + 0.5f*unc); }
    else { fv = 0.f; gv = 0.f; }
    F[(size_t)r*128 + col] = (_Float16)fv;
    G[(size_t)r*128 + col] = (_Float16)gv;
  }
  if (lane == 0){
    int mk = mask[r];
    float t = 1.f + 0.5f*explore[r] - 0.5f*exploit[r];
    t = fminf(fmaxf(t, 0.5f), 2.f);
    if (mk) t = 1.f;
    a1v[r] = 0.125f/t;
  }
}

// ---------------- NT GEMM: C[m][n] = sum_k A[m][k]*B[n][k] ----------------
// EPI 0: bf16 out (+biasv). EPI 1: f32 out +biasv +rowmask-zero.
// EPI 2: bf16 out transposed per-head -> Vt[b][h][d][s] (+biasv).
// EPI 3: f16 in/out, value*8, col-masked keys -> -inf (rowmask = key mask, batched).
template<int EPI>
__global__ __launch_bounds__(256) void gemm_nt_k(
    const short* __restrict__ A, const short* __restrict__ Bm, void* __restrict__ C,
    int Kd, int lda, int ldb, int ldc,
    long sA, long sB, long sC,
    const float* __restrict__ biasv, const int* __restrict__ rowmask)
{
  __shared__ short As[128*32];
  __shared__ short Bs[128*32];
  const short* Ab = A + (size_t)blockIdx.z*sA;
  const short* Bb = Bm + (size_t)blockIdx.z*sB;
  const int tid = threadIdx.x;
  const int wv = tid>>6, lane = tid&63, quad = lane>>4, l16 = lane&15;
  const int m0 = blockIdx.y*128, n0 = blockIdx.x*128;
  const int wm = (wv>>1)*64, wn = (wv&1)*64;
  const int rowL = tid>>2, colL = (tid&3)*8;
  fx4 acc[4][4] = {};
  for (int k0=0; k0<Kd; k0+=32){
    __syncthreads();
    async16(Ab + (size_t)(m0+rowL)*lda    + k0 + colL, &As[tid*8]);
    async16(Ab + (size_t)(m0+64+rowL)*lda + k0 + colL, &As[2048 + tid*8]);
    async16(Bb + (size_t)(n0+rowL)*ldb    + k0 + colL, &Bs[tid*8]);
    async16(Bb + (size_t)(n0+64+rowL)*ldb + k0 + colL, &Bs[2048 + tid*8]);
    __syncthreads();
    short8 af[4], bfr[4];
    #pragma unroll
    for (int mi=0; mi<4; mi++) af[mi]  = *(const short8*)&As[(wm+mi*16+l16)*32 + quad*8];
    #pragma unroll
    for (int ni=0; ni<4; ni++) bfr[ni] = *(const short8*)&Bs[(wn+ni*16+l16)*32 + quad*8];
    #pragma unroll
    for (int mi=0; mi<4; mi++)
      #pragma unroll
      for (int ni=0; ni<4; ni++){
        if constexpr (EPI == 3) acc[mi][ni] = mfma_h(af[mi], bfr[ni], acc[mi][ni]);
        else                    acc[mi][ni] = mfma_bf(af[mi], bfr[ni], acc[mi][ni]);
      }
  }
  if constexpr (EPI == 2){
    // stage transposed tile in LDS, then coalesced store to Vt[b][h][d][s]
    __shared__ short Ct[128*136];
    #pragma unroll
    for (int mi=0; mi<4; mi++)
      #pragma unroll
      for (int ni=0; ni<4; ni++){
        int lcol = wn + ni*16 + l16;
        int lrow = wm + mi*16 + quad*4;
        float b0 = biasv[n0 + lcol];
        short4v pk;
        #pragma unroll
        for (int rg=0; rg<4; rg++) pk[rg] = f2bf(acc[mi][ni][rg] + b0);
        *(short4v*)&Ct[lcol*136 + lrow] = pk;
      }
    __syncthreads();
    short* Vt = (short*)C;
    int sl = (tid&15)*8;
    int bb = m0 >> 11, s0 = m0 & 2047;
    #pragma unroll
    for (int e8=0; e8<8; e8++){
      int e_l = e8*16 + (tid>>4);
      fx4 val = *(const fx4*)&Ct[e_l*136 + sl];
      int e_g = n0 + e_l;
      size_t dst = ((size_t)(bb*Hn + (e_g>>6))*64 + (e_g&63))*Sn + s0 + sl;
      *(fx4*)&Vt[dst] = val;
    }
  } else {
    #pragma unroll
    for (int mi=0; mi<4; mi++){
      #pragma unroll
      for (int ni=0; ni<4; ni++){
        #pragma unroll
        for (int rg=0; rg<4; rg++){
          int row = m0 + wm + mi*16 + quad*4 + rg;   // C/D: row=quad*4+reg, col=lane&15 (m89)
          int col = n0 + wn + ni*16 + l16;
          float v = acc[mi][ni][rg];
          if constexpr (EPI == 0){
            v += biasv[col];
            ((short*)C)[(size_t)row*ldc + col] = f2bf(v);
          } else if constexpr (EPI == 1){
            v += biasv[col];
            if (rowmask[row]) v = 0.f;
            ((float*)C)[(size_t)row*ldc + col] = v;
          } else { // EPI == 3: f16 out, x8 pre-scale, masked key-cols -> -inf (exact)
            _Float16 hv;
            if (rowmask[blockIdx.z*Sn + col]) hv = __builtin_bit_cast(_Float16, (unsigned short)0xFC00);
            else hv = (_Float16)(v*8.f);
            ((_Float16*)C + (size_t)blockIdx.z*sC)[(size_t)row*ldc + col] = hv;
          }
        }
      }
    }
  }
}

// ---------------- flash attention v3 ----------------
// 128q block, 32q/wave. S^T via 32x32x16 (A=K, B=Q) so lane-col = q is fixed;
// P moves to PV B-operand with 2 shfl_xor(32) per 16-s chunk (no LDS round-trip).
// o^T = V^T P^T accumulated 64d x 32q per wave. Double-buffered K/Vt tiles with
// prefetch-one-ahead; bias f16 [b][q][s] (x8 pre-scale, -inf at masked keys)
// loaded to regs one tile ahead. No softmax shift (scale-invariant, logits small).
__global__ __launch_bounds__(256, 3) void flash3_k(
    const short* __restrict__ Qg, const short* __restrict__ Kg, const short* __restrict__ Vtg,
    const _Float16* __restrict__ biasQ, const float* __restrict__ a1v,
    short* __restrict__ AO)
{
  __shared__ short smem[2][2][64*64];   // [buf][K/Vt][tile]  = 32 KB
  const int tid = threadIdx.x, wv = tid>>6, lane = tid&63;
  const int l32 = lane&31, hi = lane>>5;
  const int q0 = blockIdx.x*128;
  const int b = blockIdx.y >> 4, h = blockIdx.y & 15;
  const short* Qb  = Qg  + (size_t)b*Sn*En + h*64;
  const short* Kb  = Kg  + (size_t)b*Sn*En + h*64;
  const short* Vtb = Vtg + (size_t)(b*Hn + h)*64*Sn;
  const int q = q0 + wv*32 + l32;
  const _Float16* bq_l = biasQ + ((size_t)b*Sn + q)*Sn;
  const float a1 = a1v[b*Sn + q];

  auto issue = [&](int kt, int buf){
    #pragma unroll
    for (int rnd=0; rnd<2; rnd++){
      int idx = rnd*256 + tid;
      int r = idx>>3, c = (idx&7) ^ (r&7);     // XOR swizzle on global side
      async16(Kb  + (size_t)(kt + r)*En + c*8, &smem[buf][0][idx*8]);
      async16(Vtb + (size_t)r*Sn + kt + c*8,   &smem[buf][1][idx*8]);
    }
  };
  issue(0, 0);

  // Q B-frags straight from global: B[n=q][k=c*16+hi*8+j]
  short8 qf[4];
  #pragma unroll
  for (int c=0; c<4; c++)
    qf[c] = *(const short8*)(Qb + (size_t)q*En + c*16 + hi*8);

  half4 bh[8];   // bias for current tile: [t*4+rq] = s in {t*32 + rq*8 + hi*4 .. +3}
  #pragma unroll
  for (int i=0; i<8; i++)
    bh[i] = *(const half4*)(bq_l + (i>>2)*32 + (i&3)*8 + hi*4);

  fx16 o0 = {}, o1 = {};
  float psum = 0.f;

  #pragma unroll 2
  for (int T=0; T<32; T++){
    const int kt = T*64, buf = T&1;
    __syncthreads();                      // tile T resident; buf^1 free
    if (T < 31) issue(kt+64, buf^1);
    half4 bhn[8];
    if (T < 31){
      #pragma unroll
      for (int i=0; i<8; i++)
        bhn[i] = *(const half4*)(bq_l + kt + 64 + (i>>2)*32 + (i&3)*8 + hi*4);
    }
    short8 pfr[4];                        // PV B-frags per 16-s chunk
    #pragma unroll
    for (int t=0; t<2; t++){              // s-strip of 32
      int r = t*32 + l32;
      short8 ka[4];
      #pragma unroll
      for (int c=0; c<4; c++){
        int g = (c*2 + hi) ^ (r&7);
        ka[c] = *(const short8*)&smem[buf][0][r*64 + g*8];
      }
      fx16 sa = {};
      #pragma unroll
      for (int c=0; c<4; c++) sa = mfma32(ka[c], qf[c], sa);
      // p = exp((sacc + 8*bias) * a1); -inf bias at masked keys -> p = 0
      float p[16];
      #pragma unroll
      for (int rr=0; rr<16; rr++){
        float ba = (float)bh[t*4 + (rr>>2)][rr&3] * a1;
        p[rr] = __expf(fmaf(sa[rr], a1, ba));
        psum += p[rr];
      }
      // pack pairs, half-wave exchange -> B-operand layout (k = hi*8+j)
      #pragma unroll
      for (int c2=0; c2<2; c2++){
        int base = c2*8;
        int d0 = pk2(p[base+0], p[base+1]);
        int d1 = pk2(p[base+2], p[base+3]);
        int d2 = pk2(p[base+4], p[base+5]);
        int d3 = pk2(p[base+6], p[base+7]);
        int s0 = hi ? d0 : d2;
        int s1 = hi ? d1 : d3;
        int r0 = __shfl_xor(s0, 32, 64);
        int r1 = __shfl_xor(s1, 32, 64);
        ix4 fr = { hi ? r0 : d0, hi ? r1 : d1, hi ? d2 : r0, hi ? d3 : r1 };
        pfr[t*2 + c2] = __builtin_bit_cast(short8, fr);
      }
    }
    // o^T += V^T P^T : A[m=d][k=s] from Vt, B[n=q][k=s] = pfr
    #pragma unroll
    for (int ds=0; ds<2; ds++){
      int r = ds*32 + l32;
      #pragma unroll
      for (int sc=0; sc<4; sc++){
        int g = (sc*2 + hi) ^ (r&7);
        short8 va = *(const short8*)&smem[buf][1][r*64 + g*8];
        if (ds == 0) o0 = mfma32(va, pfr[sc], o0);
        else         o1 = mfma32(va, pfr[sc], o1);
      }
    }
    if (T < 31){
      #pragma unroll
      for (int i=0; i<8; i++) bh[i] = bhn[i];
    }
  }

  psum += __shfl_xor(psum, 32, 64);
  float linv = 1.f/fmaxf(psum, 1e-30f);

  // epilogue: stage o^T -> LDS [q][d] (stride 72), then coalesced b128 stores
  __syncthreads();
  short* stage = &smem[0][0][0] + wv*2304;   // 32*72 shorts per wave
  #pragma unroll
  for (int ds=0; ds<2; ds++){
    const fx16& o = ds ? o1 : o0;
    #pragma unroll
    for (int rq=0; rq<4; rq++){
      int d0 = ds*32 + rq*8 + hi*4;
      short4v pk;
      #pragma unroll
      for (int j=0; j<4; j++) pk[j] = f2bf(o[rq*4 + j]*linv);
      *(short4v*)&stage[l32*72 + d0] = pk;
    }
  }
  short* AOb = AO + (size_t)b*Sn*En + h*64;
  #pragma unroll
  for (int rnd=0; rnd<4; rnd++){
    int idx = rnd*64 + lane;
    int r = idx>>3, ch = idx&7;
    fx4 val = *(const fx4*)&stage[r*72 + ch*8];
    *(fx4*)(AOb + (size_t)(q0 + wv*32 + r)*En + ch*8) = val;
  }
}

extern "C" void kernel_launch(void* const* d_in, const int* in_sizes, int n_in,
                              void* d_out, int out_size, void* d_ws, size_t ws_size,
                              hipStream_t stream)
{
  const float* his     = (const float*)d_in[0];
  const int*   mask    = (const int*)  d_in[1];
  const float* mu      = (const float*)d_in[2];
  const float* sigma   = (const float*)d_in[3];
  const float* assign  = (const float*)d_in[4];
  const float* explore = (const float*)d_in[5];
  const float* exploit = (const float*)d_in[6];
  const float* Wq = (const float*)d_in[7];  const float* bq = (const float*)d_in[8];
  const float* Wk = (const float*)d_in[9];  const float* bk = (const float*)d_in[10];
  const float* Wv = (const float*)d_in[11]; const float* bv = (const float*)d_in[12];
  const float* Wo = (const float*)d_in[13]; const float* bo = (const float*)d_in[14];

  char* w = (char*)d_ws;
  size_t off = 0;
  auto alloc = [&](size_t bytes){ void* p = w + off; off += (bytes + 255) & ~(size_t)255; return p; };
  short*     Xb    = (short*)alloc((size_t)BSn*En*2);
  short*     Wqb   = (short*)alloc((size_t)En*En*2);
  short*     Wkb   = (short*)alloc((size_t)En*En*2);
  short*     Wvb   = (short*)alloc((size_t)En*En*2);
  short*     Wob   = (short*)alloc((size_t)En*En*2);
  short*     Qb    = (short*)alloc((size_t)BSn*En*2);
  short*     Kb    = (short*)alloc((size_t)BSn*En*2);
  short*     Vtg   = (short*)alloc((size_t)BSn*En*2);
  short*     AO    = (short*)alloc((size_t)BSn*En*2);
  _Float16*  F     = (_Float16*)alloc((size_t)BSn*128*2);
  _Float16*  G     = (_Float16*)alloc((size_t)BSn*128*2);
  _Float16*  biasQ = (_Float16*)alloc((size_t)Bn*Sn*Sn*2);
  float*     a1vp  = (float*)alloc((size_t)BSn*4);
  (void)ws_size; (void)in_sizes; (void)n_in; (void)out_size;

  cast_bf16_k<<<(BSn*En/4 + 255)/256, 256, 0, stream>>>(his, Xb, BSn*En/4);
  cast_bf16_k<<<(En*En/4 + 255)/256, 256, 0, stream>>>(Wq, Wqb, En*En/4);
  cast_bf16_k<<<(En*En/4 + 255)/256, 256, 0, stream>>>(Wk, Wkb, En*En/4);
  cast_bf16_k<<<(En*En/4 + 255)/256, 256, 0, stream>>>(Wv, Wvb, En*En/4);
  cast_bf16_k<<<(En*En/4 + 255)/256, 256, 0, stream>>>(Wo, Wob, En*En/4);
  prep_rows_k<<<BSn, 64, 0, stream>>>(mu, sigma, assign, explore, exploit, mask, F, G, a1vp);
  // Q,K projections (normal layout), V projection (transposed per-head layout)
  gemm_nt_k<0><<<dim3(En/128, BSn/128, 1), 256, 0, stream>>>(Xb, Wqb, Qb, En, En, En, En, 0,0,0, bq, nullptr);
  gemm_nt_k<0><<<dim3(En/128, BSn/128, 1), 256, 0, stream>>>(Xb, Wkb, Kb, En, En, En, En, 0,0,0, bk, nullptr);
  gemm_nt_k<2><<<dim3(En/128, BSn/128, 1), 256, 0, stream>>>(Xb, Wvb, Vtg, En, En, En, En, 0,0,0, bv, nullptr);
  // bias matrix [b][q][s] = 8 * (F[b] @ G[b]^T), f16, masked key-cols = -inf
  gemm_nt_k<3><<<dim3(Sn/128, Sn/128, Bn), 256, 0, stream>>>(
      (const short*)F, (const short*)G, biasQ, 128, 128, 128, Sn,
      (long)Sn*128, (long)Sn*128, (long)Sn*Sn, nullptr, mask);
  flash3_k<<<dim3(Sn/128, Bn*Hn), 256, 0, stream>>>(Qb, Kb, Vtg, biasQ, a1vp, AO);
  gemm_nt_k<1><<<dim3(En/128, BSn/128, 1), 256, 0, stream>>>(AO, Wob, d_out, En, En, En, En, 0,0,0, bo, mask);
}

// Round 5
// 410.117 us; speedup vs baseline: 1.2834x; 1.2834x over previous
//
#include <hip/hip_runtime.h>
#include <hip/hip_bf16.h>
#include <stdint.h>
#include <stddef.h>

#define Bn 4
#define Sn 2048
#define En 1024
#define Hn 16
#define DIn 64
#define BSn (Bn*Sn)   // 8192

typedef __attribute__((ext_vector_type(8))) short short8;
typedef __attribute__((ext_vector_type(4))) short short4v;
typedef __attribute__((ext_vector_type(4))) float fx4;
typedef __attribute__((ext_vector_type(16))) float fx16;
typedef __attribute__((ext_vector_type(8))) _Float16 half8;
typedef __attribute__((ext_vector_type(4))) _Float16 half4;
typedef __attribute__((ext_vector_type(4))) int ix4;

__device__ __forceinline__ short f2bf(float f){
  union U { __hip_bfloat16 h; short s; } u; u.h = __float2bfloat16(f); return u.s;
}
__device__ __forceinline__ int pk2(float a, float b){
  unsigned lo = (unsigned short)f2bf(a);
  unsigned hi = (unsigned short)f2bf(b);
  return (int)(lo | (hi << 16));
}

__device__ __forceinline__ void async16(const void* g, void* l){
  __builtin_amdgcn_global_load_lds((const __attribute__((address_space(1))) unsigned int*)g,
                                   (__attribute__((address_space(3))) unsigned int*)l, 16, 0, 0);
}

__device__ __forceinline__ fx4 mfma_bf(short8 a, short8 b, fx4 c){
  return __builtin_amdgcn_mfma_f32_16x16x32_bf16(a, b, c, 0, 0, 0);
}
__device__ __forceinline__ fx4 mfma_h(short8 a, short8 b, fx4 c){
  return __builtin_amdgcn_mfma_f32_16x16x32_f16(__builtin_bit_cast(half8, a),
                                                __builtin_bit_cast(half8, b), c, 0, 0, 0);
}
__device__ __forceinline__ fx16 mfma32(short8 a, short8 b, fx16 c){
  return __builtin_amdgcn_mfma_f32_32x32x16_bf16(a, b, c, 0, 0, 0);
}

// ---------------- cast f32 -> bf16 (vectorized x4) ----------------
__global__ void cast_bf16_k(const float* __restrict__ in, short* __restrict__ out, int n4){
  int i = blockIdx.x*256 + threadIdx.x;
  if (i >= n4) return;
  fx4 v = ((const fx4*)in)[i];
  short4v o = { f2bf(v[0]), f2bf(v[1]), f2bf(v[2]), f2bf(v[3]) };
  ((short4v*)out)[i] = o;
}

// ---------------- per-(b,s) row prep ----------------
// bias(q,k) = F_q . G_k ; a1v = 0.125*invT (logit = (qk + 8*bias)*a1)
__global__ void prep_rows_k(const float* __restrict__ mu, const float* __restrict__ sigma,
                            const float* __restrict__ assign, const float* __restrict__ explore,
                            const float* __restrict__ exploit, const int* __restrict__ mask,
                            _Float16* __restrict__ F, _Float16* __restrict__ G,
                            float* __restrict__ a1v){
  int r = blockIdx.x;          // 0..BSn-1
  int lane = threadIdx.x;      // 64
  float muv = mu[(size_t)r*DIn + lane];
  float sgv = sigma[(size_t)r*DIn + lane];
  float sq = muv*muv, sg = sgv;
  #pragma unroll
  for (int m=32; m; m>>=1){ sq += __shfl_xor(sq,m,64); sg += __shfl_xor(sg,m,64); }
  float unc = sg*(1.f/64.f);
  #pragma unroll
  for (int cb=0; cb<128; cb+=64){
    int col = cb + lane;
    float fv, gv;
    if (col < 32){ float a = assign[(size_t)r*32 + col]; fv = 0.5f*a; gv = a; }
    else if (col < 96){ float m2 = mu[(size_t)r*DIn + (col-32)]; fv = m2*(1.f/64.f); gv = m2; }
    else if (col == 96){ fv = -sq*(1.f/128.f); gv = 1.f; }
    else if (col == 97){ fv = 1.f; gv = -(sq*(1.f/128.f) + 0.5f*unc); }
    else { fv = 0.f; gv = 0.f; }
    F[(size_t)r*128 + col] = (_Float16)fv;
    G[(size_t)r*128 + col] = (_Float16)gv;
  }
  if (lane == 0){
    int mk = mask[r];
    float t = 1.f + 0.5f*explore[r] - 0.5f*exploit[r];
    t = fminf(fmaxf(t, 0.5f), 2.f);
    if (mk) t = 1.f;
    a1v[r] = 0.125f/t;
  }
}

// ---------------- fused QKV GEMM: X(8192x1024) @ WQKV(3072x1024)^T ----------------
// seg 0 -> Q (bf16 [row][1024]), seg 1 -> K, seg 2 -> V transposed per-head Vt[b][h][d][s].
__global__ __launch_bounds__(256) void gemm_qkv_k(
    const short* __restrict__ A, const short* __restrict__ Wqkv,
    short* __restrict__ Q, short* __restrict__ K, short* __restrict__ Vt,
    const float* __restrict__ bq, const float* __restrict__ bk, const float* __restrict__ bv)
{
  __shared__ short As[128*32];
  __shared__ short Bs[128*32];
  __shared__ short Ct[128*136];
  const int tid = threadIdx.x;
  const int wv = tid>>6, lane = tid&63, quad = lane>>4, l16 = lane&15;
  const int m0 = blockIdx.y*128, n0g = blockIdx.x*128;
  const int seg = n0g >> 10, nloc = n0g & 1023;
  const int wm = (wv>>1)*64, wn = (wv&1)*64;
  const int rowL = tid>>2, colL = (tid&3)*8;
  fx4 acc[4][4] = {};
  for (int k0=0; k0<En; k0+=32){
    __syncthreads();
    async16(A    + (size_t)(m0+rowL)*En     + k0 + colL, &As[tid*8]);
    async16(A    + (size_t)(m0+64+rowL)*En  + k0 + colL, &As[2048 + tid*8]);
    async16(Wqkv + (size_t)(n0g+rowL)*En    + k0 + colL, &Bs[tid*8]);
    async16(Wqkv + (size_t)(n0g+64+rowL)*En + k0 + colL, &Bs[2048 + tid*8]);
    __syncthreads();
    short8 af[4], bfr[4];
    #pragma unroll
    for (int mi=0; mi<4; mi++) af[mi]  = *(const short8*)&As[(wm+mi*16+l16)*32 + quad*8];
    #pragma unroll
    for (int ni=0; ni<4; ni++) bfr[ni] = *(const short8*)&Bs[(wn+ni*16+l16)*32 + quad*8];
    #pragma unroll
    for (int mi=0; mi<4; mi++)
      #pragma unroll
      for (int ni=0; ni<4; ni++)
        acc[mi][ni] = mfma_bf(af[mi], bfr[ni], acc[mi][ni]);
  }
  const float* biasv = (seg == 0) ? bq : (seg == 1) ? bk : bv;
  if (seg < 2){
    short* C = seg ? K : Q;
    #pragma unroll
    for (int mi=0; mi<4; mi++)
      #pragma unroll
      for (int ni=0; ni<4; ni++){
        int col = nloc + wn + ni*16 + l16;
        float b0 = biasv[col];
        #pragma unroll
        for (int rg=0; rg<4; rg++){
          int row = m0 + wm + mi*16 + quad*4 + rg;
          C[(size_t)row*En + col] = f2bf(acc[mi][ni][rg] + b0);
        }
      }
  } else {
    // stage transposed tile in LDS, then coalesced store to Vt[b][h][d][s]
    #pragma unroll
    for (int mi=0; mi<4; mi++)
      #pragma unroll
      for (int ni=0; ni<4; ni++){
        int lcol = wn + ni*16 + l16;
        int lrow = wm + mi*16 + quad*4;
        float b0 = biasv[nloc + lcol];
        short4v pk;
        #pragma unroll
        for (int rg=0; rg<4; rg++) pk[rg] = f2bf(acc[mi][ni][rg] + b0);
        *(short4v*)&Ct[lcol*136 + lrow] = pk;
      }
    __syncthreads();
    int sl = (tid&15)*8;
    int bb = m0 >> 11, s0 = m0 & 2047;
    #pragma unroll
    for (int e8=0; e8<8; e8++){
      int e_l = e8*16 + (tid>>4);
      fx4 val = *(const fx4*)&Ct[e_l*136 + sl];
      int e_g = nloc + e_l;
      size_t dst = ((size_t)(bb*Hn + (e_g>>6))*64 + (e_g&63))*Sn + s0 + sl;
      *(fx4*)&Vt[dst] = val;
    }
  }
}

// ---------------- NT GEMM (bias matrix + output projection) ----------------
// EPI 1: f32 out +biasv +rowmask-zero. EPI 3: f16 in/out, x8, masked key-cols -> -inf.
template<int EPI>
__global__ __launch_bounds__(256) void gemm_nt_k(
    const short* __restrict__ A, const short* __restrict__ Bm, void* __restrict__ C,
    int Kd, int lda, int ldb, int ldc,
    long sA, long sB, long sC,
    const float* __restrict__ biasv, const int* __restrict__ rowmask)
{
  __shared__ short As[128*32];
  __shared__ short Bs[128*32];
  const short* Ab = A + (size_t)blockIdx.z*sA;
  const short* Bb = Bm + (size_t)blockIdx.z*sB;
  const int tid = threadIdx.x;
  const int wv = tid>>6, lane = tid&63, quad = lane>>4, l16 = lane&15;
  const int m0 = blockIdx.y*128, n0 = blockIdx.x*128;
  const int wm = (wv>>1)*64, wn = (wv&1)*64;
  const int rowL = tid>>2, colL = (tid&3)*8;
  fx4 acc[4][4] = {};
  for (int k0=0; k0<Kd; k0+=32){
    __syncthreads();
    async16(Ab + (size_t)(m0+rowL)*lda    + k0 + colL, &As[tid*8]);
    async16(Ab + (size_t)(m0+64+rowL)*lda + k0 + colL, &As[2048 + tid*8]);
    async16(Bb + (size_t)(n0+rowL)*ldb    + k0 + colL, &Bs[tid*8]);
    async16(Bb + (size_t)(n0+64+rowL)*ldb + k0 + colL, &Bs[2048 + tid*8]);
    __syncthreads();
    short8 af[4], bfr[4];
    #pragma unroll
    for (int mi=0; mi<4; mi++) af[mi]  = *(const short8*)&As[(wm+mi*16+l16)*32 + quad*8];
    #pragma unroll
    for (int ni=0; ni<4; ni++) bfr[ni] = *(const short8*)&Bs[(wn+ni*16+l16)*32 + quad*8];
    #pragma unroll
    for (int mi=0; mi<4; mi++)
      #pragma unroll
      for (int ni=0; ni<4; ni++){
        if constexpr (EPI == 3) acc[mi][ni] = mfma_h(af[mi], bfr[ni], acc[mi][ni]);
        else                    acc[mi][ni] = mfma_bf(af[mi], bfr[ni], acc[mi][ni]);
      }
  }
  #pragma unroll
  for (int mi=0; mi<4; mi++){
    #pragma unroll
    for (int ni=0; ni<4; ni++){
      #pragma unroll
      for (int rg=0; rg<4; rg++){
        int row = m0 + wm + mi*16 + quad*4 + rg;   // C/D: row=quad*4+reg, col=lane&15 (m89)
        int col = n0 + wn + ni*16 + l16;
        float v = acc[mi][ni][rg];
        if constexpr (EPI == 1){
          v += biasv[col];
          if (rowmask[row]) v = 0.f;
          ((float*)C)[(size_t)row*ldc + col] = v;
        } else { // EPI == 3: f16 out, x8 pre-scale, masked key-cols -> -inf (exact)
          _Float16 hv;
          if (rowmask[blockIdx.z*Sn + col]) hv = __builtin_bit_cast(_Float16, (unsigned short)0xFC00);
          else hv = (_Float16)(v*8.f);
          ((_Float16*)C + (size_t)blockIdx.z*sC)[(size_t)row*ldc + col] = hv;
        }
      }
    }
  }
}

// ---------------- flash attention v4 (de-spilled v3) ----------------
// 128q block, 32q/wave. S^T via 32x32x16 (A=K, B=Q); P -> PV B-operand with
// 2 shfl_xor(32) per strip (no LDS round-trip). PV strip-interleaved so P frags
// are transient. Single-level bias prefetch per tile (L3-resident). Double-
// buffered K/Vt tiles, prefetch-one-ahead. No softmax shift (scale-invariant).
__global__ __launch_bounds__(256, 3) void flash4_k(
    const short* __restrict__ Qg, const short* __restrict__ Kg, const short* __restrict__ Vtg,
    const _Float16* __restrict__ biasQ, const float* __restrict__ a1v,
    short* __restrict__ AO)
{
  __shared__ short smem[2][2][64*64];   // [buf][K/Vt][tile]  = 32 KB
  const int tid = threadIdx.x, wv = tid>>6, lane = tid&63;
  const int l32 = lane&31, hi = lane>>5;
  const int q0 = blockIdx.x*128;
  const int b = blockIdx.y >> 4, h = blockIdx.y & 15;
  const short* Qb  = Qg  + (size_t)b*Sn*En + h*64;
  const short* Kb  = Kg  + (size_t)b*Sn*En + h*64;
  const short* Vtb = Vtg + (size_t)(b*Hn + h)*64*Sn;
  const int q = q0 + wv*32 + l32;
  const _Float16* bq_l = biasQ + ((size_t)b*Sn + q)*Sn;
  const float a1 = a1v[b*Sn + q];

  auto issue = [&](int kt, int buf){
    #pragma unroll
    for (int rnd=0; rnd<2; rnd++){
      int idx = rnd*256 + tid;
      int r = idx>>3, c = (idx&7) ^ (r&7);     // XOR swizzle on global side
      async16(Kb  + (size_t)(kt + r)*En + c*8, &smem[buf][0][idx*8]);
      async16(Vtb + (size_t)r*Sn + kt + c*8,   &smem[buf][1][idx*8]);
    }
  };
  issue(0, 0);

  // Q B-frags straight from global: B[n=q][k=c*16+hi*8+j]
  short8 qf[4];
  #pragma unroll
  for (int c=0; c<4; c++)
    qf[c] = *(const short8*)(Qb + (size_t)q*En + c*16 + hi*8);

  fx16 o0 = {}, o1 = {};
  float psum = 0.f;

  for (int T=0; T<32; T++){
    const int kt = T*64, buf = T&1;
    __syncthreads();                      // tile T resident; buf^1 free
    if (T < 31) issue(kt+64, buf^1);
    // bias for this tile: 8x half4 per lane ([q][s] layout, L3-resident)
    half4 bh[8];
    #pragma unroll
    for (int i=0; i<8; i++)
      bh[i] = *(const half4*)(bq_l + kt + (i>>2)*32 + (i&3)*8 + hi*4);

    #pragma unroll
    for (int t=0; t<2; t++){              // s-strip of 32
      int r = t*32 + l32;
      fx16 sa = {};
      #pragma unroll
      for (int c=0; c<4; c++){
        int g = (c*2 + hi) ^ (r&7);
        short8 ka = *(const short8*)&smem[buf][0][r*64 + g*8];
        sa = mfma32(ka, qf[c], sa);
      }
      // p = exp((sacc + 8*bias) * a1); -inf bias at masked keys -> p = 0
      float p[16];
      #pragma unroll
      for (int rr=0; rr<16; rr++){
        float ba = (float)bh[t*4 + (rr>>2)][rr&3] * a1;
        p[rr] = __expf(fmaf(sa[rr], a1, ba));
        psum += p[rr];
      }
      // pack pairs, half-wave exchange -> B-operand layout (k = hi*8+j)
      #pragma unroll
      for (int c2=0; c2<2; c2++){
        int base = c2*8;
        int d0 = pk2(p[base+0], p[base+1]);
        int d1 = pk2(p[base+2], p[base+3]);
        int d2 = pk2(p[base+4], p[base+5]);
        int d3 = pk2(p[base+6], p[base+7]);
        int s0 = hi ? d0 : d2;
        int s1 = hi ? d1 : d3;
        int r0 = __shfl_xor(s0, 32, 64);
        int r1 = __shfl_xor(s1, 32, 64);
        ix4 fr = { hi ? r0 : d0, hi ? r1 : d1, hi ? d2 : r0, hi ? d3 : r1 };
        short8 pf = __builtin_bit_cast(short8, fr);
        // PV partial for this strip chunk: sc = t*2+c2 covers s = 32t+16c2..
        int sc = t*2 + c2;
        #pragma unroll
        for (int ds=0; ds<2; ds++){
          int rv = ds*32 + l32;
          int gv = (sc*2 + hi) ^ (rv&7);
          short8 va = *(const short8*)&smem[buf][1][rv*64 + gv*8];
          if (ds == 0) o0 = mfma32(va, pf, o0);
          else         o1 = mfma32(va, pf, o1);
        }
      }
    }
  }

  psum += __shfl_xor(psum, 32, 64);
  float linv = 1.f/fmaxf(psum, 1e-30f);

  // epilogue: stage o^T -> LDS [q][d] (stride 72), then coalesced b128 stores
  __syncthreads();
  short* stage = &smem[0][0][0] + wv*2304;   // 32*72 shorts per wave
  #pragma unroll
  for (int ds=0; ds<2; ds++){
    const fx16& o = ds ? o1 : o0;
    #pragma unroll
    for (int rq=0; rq<4; rq++){
      int d0 = ds*32 + rq*8 + hi*4;
      short4v pk;
      #pragma unroll
      for (int j=0; j<4; j++) pk[j] = f2bf(o[rq*4 + j]*linv);
      *(short4v*)&stage[l32*72 + d0] = pk;
    }
  }
  short* AOb = AO + (size_t)b*Sn*En + h*64;
  #pragma unroll
  for (int rnd=0; rnd<4; rnd++){
    int idx = rnd*64 + lane;
    int r = idx>>3, ch = idx&7;
    fx4 val = *(const fx4*)&stage[r*72 + ch*8];
    *(fx4*)(AOb + (size_t)(q0 + wv*32 + r)*En + ch*8) = val;
  }
}

extern "C" void kernel_launch(void* const* d_in, const int* in_sizes, int n_in,
                              void* d_out, int out_size, void* d_ws, size_t ws_size,
                              hipStream_t stream)
{
  const float* his     = (const float*)d_in[0];
  const int*   mask    = (const int*)  d_in[1];
  const float* mu      = (const float*)d_in[2];
  const float* sigma   = (const float*)d_in[3];
  const float* assign  = (const float*)d_in[4];
  const float* explore = (const float*)d_in[5];
  const float* exploit = (const float*)d_in[6];
  const float* Wq = (const float*)d_in[7];  const float* bq = (const float*)d_in[8];
  const float* Wk = (const float*)d_in[9];  const float* bk = (const float*)d_in[10];
  const float* Wv = (const float*)d_in[11]; const float* bv = (const float*)d_in[12];
  const float* Wo = (const float*)d_in[13]; const float* bo = (const float*)d_in[14];

  char* w = (char*)d_ws;
  size_t off = 0;
  auto alloc = [&](size_t bytes){ void* p = w + off; off += (bytes + 255) & ~(size_t)255; return p; };
  short*     Xb    = (short*)alloc((size_t)BSn*En*2);
  short*     WQKV  = (short*)alloc((size_t)3*En*En*2);
  short*     Wob   = (short*)alloc((size_t)En*En*2);
  short*     Qb    = (short*)alloc((size_t)BSn*En*2);
  short*     Kb    = (short*)alloc((size_t)BSn*En*2);
  short*     Vtg   = (short*)alloc((size_t)BSn*En*2);
  short*     AO    = (short*)alloc((size_t)BSn*En*2);
  _Float16*  F     = (_Float16*)alloc((size_t)BSn*128*2);
  _Float16*  G     = (_Float16*)alloc((size_t)BSn*128*2);
  _Float16*  biasQ = (_Float16*)alloc((size_t)Bn*Sn*Sn*2);
  float*     a1vp  = (float*)alloc((size_t)BSn*4);
  (void)ws_size; (void)in_sizes; (void)n_in; (void)out_size;

  cast_bf16_k<<<(BSn*En/4 + 255)/256, 256, 0, stream>>>(his, Xb, BSn*En/4);
  cast_bf16_k<<<(En*En/4 + 255)/256, 256, 0, stream>>>(Wq, WQKV,            En*En/4);
  cast_bf16_k<<<(En*En/4 + 255)/256, 256, 0, stream>>>(Wk, WQKV + En*En,    En*En/4);
  cast_bf16_k<<<(En*En/4 + 255)/256, 256, 0, stream>>>(Wv, WQKV + 2*En*En,  En*En/4);
  cast_bf16_k<<<(En*En/4 + 255)/256, 256, 0, stream>>>(Wo, Wob, En*En/4);
  prep_rows_k<<<BSn, 64, 0, stream>>>(mu, sigma, assign, explore, exploit, mask, F, G, a1vp);
  // fused Q/K/V projection (V stored transposed per-head)
  gemm_qkv_k<<<dim3(3*En/128, BSn/128), 256, 0, stream>>>(Xb, WQKV, Qb, Kb, Vtg, bq, bk, bv);
  // bias matrix [b][q][s] = 8 * (F[b] @ G[b]^T), f16, masked key-cols = -inf
  gemm_nt_k<3><<<dim3(Sn/128, Sn/128, Bn), 256, 0, stream>>>(
      (const short*)F, (const short*)G, biasQ, 128, 128, 128, Sn,
      (long)Sn*128, (long)Sn*128, (long)Sn*Sn, nullptr, mask);
  flash4_k<<<dim3(Sn/128, Bn*Hn), 256, 0, stream>>>(Qb, Kb, Vtg, biasQ, a1vp, AO);
  gemm_nt_k<1><<<dim3(En/128, BSn/128, 1), 256, 0, stream>>>(AO, Wob, d_out, En, En, En, En, 0,0,0, bo, mask);
}

// Round 6
// 341.582 us; speedup vs baseline: 1.5410x; 1.2006x over previous
//
#include <hip/hip_runtime.h>
#include <hip/hip_bf16.h>
#include <stdint.h>
#include <stddef.h>

#define Bn 4
#define Sn 2048
#define En 1024
#define Hn 16
#define DIn 64
#define BSn (Bn*Sn)   // 8192
#define L2E 1.44269504089f
#define SH8L 11.5415603271f   // 8*log2(e)

typedef __attribute__((ext_vector_type(8))) short short8;
typedef __attribute__((ext_vector_type(4))) short short4v;
typedef __attribute__((ext_vector_type(4))) float fx4;
typedef __attribute__((ext_vector_type(16))) float fx16;
typedef __attribute__((ext_vector_type(8))) _Float16 half8;
typedef __attribute__((ext_vector_type(2))) _Float16 half2v;
typedef __attribute__((ext_vector_type(4))) int ix4;

__device__ __forceinline__ short f2bf(float f){
  union U { __hip_bfloat16 h; short s; } u; u.h = __float2bfloat16(f); return u.s;
}
__device__ __forceinline__ short f2h(float f){
  _Float16 h = (_Float16)f; return __builtin_bit_cast(short, h);
}

__device__ __forceinline__ void async16(const void* g, void* l){
  __builtin_amdgcn_global_load_lds((const __attribute__((address_space(1))) unsigned int*)g,
                                   (__attribute__((address_space(3))) unsigned int*)l, 16, 0, 0);
}

__device__ __forceinline__ fx4 mfma_bf(short8 a, short8 b, fx4 c){
  return __builtin_amdgcn_mfma_f32_16x16x32_bf16(a, b, c, 0, 0, 0);
}
__device__ __forceinline__ fx4 mfma_h(short8 a, short8 b, fx4 c){
  return __builtin_amdgcn_mfma_f32_16x16x32_f16(__builtin_bit_cast(half8, a),
                                                __builtin_bit_cast(half8, b), c, 0, 0, 0);
}
__device__ __forceinline__ fx16 mfma32h(short8 a, short8 b, fx16 c){
  return __builtin_amdgcn_mfma_f32_32x32x16_f16(__builtin_bit_cast(half8, a),
                                                __builtin_bit_cast(half8, b), c, 0, 0, 0);
}

// ---------------- casts f32 -> bf16 / f16 (vectorized x4) ----------------
__global__ void cast_bf16_k(const float* __restrict__ in, short* __restrict__ out, int n4){
  int i = blockIdx.x*256 + threadIdx.x;
  if (i >= n4) return;
  fx4 v = ((const fx4*)in)[i];
  short4v o = { f2bf(v[0]), f2bf(v[1]), f2bf(v[2]), f2bf(v[3]) };
  ((short4v*)out)[i] = o;
}
__global__ void cast_f16_k(const float* __restrict__ in, short* __restrict__ out, int n4){
  int i = blockIdx.x*256 + threadIdx.x;
  if (i >= n4) return;
  fx4 v = ((const fx4*)in)[i];
  short4v o = { f2h(v[0]), f2h(v[1]), f2h(v[2]), f2h(v[3]) };
  ((short4v*)out)[i] = o;
}

// ---------------- per-(b,s) row prep ----------------
// bias(q,k) = F_q . G_k ; a1L = 0.125*invT*log2e  (p = exp2(qk*a1L + btf))
__global__ void prep_rows_k(const float* __restrict__ mu, const float* __restrict__ sigma,
                            const float* __restrict__ assign, const float* __restrict__ explore,
                            const float* __restrict__ exploit, const int* __restrict__ mask,
                            _Float16* __restrict__ F, _Float16* __restrict__ G,
                            float* __restrict__ a1L){
  int r = blockIdx.x;          // 0..BSn-1
  int lane = threadIdx.x;      // 64
  float muv = mu[(size_t)r*DIn + lane];
  float sgv = sigma[(size_t)r*DIn + lane];
  float sq = muv*muv, sg = sgv;
  #pragma unroll
  for (int m=32; m; m>>=1){ sq += __shfl_xor(sq,m,64); sg += __shfl_xor(sg,m,64); }
  float unc = sg*(1.f/64.f);
  #pragma unroll
  for (int cb=0; cb<128; cb+=64){
    int col = cb + lane;
    float fv, gv;
    if (col < 32){ float a = assign[(size_t)r*32 + col]; fv = 0.5f*a; gv = a; }
    else if (col < 96){ float m2 = mu[(size_t)r*DIn + (col-32)]; fv = m2*(1.f/64.f); gv = m2; }
    else if (col == 96){ fv = -sq*(1.f/128.f); gv = 1.f; }
    else if (col == 97){ fv = 1.f; gv = -(sq*(1.f/128.f) + 0.5f*unc); }
    else { fv = 0.f; gv = 0.f; }
    F[(size_t)r*128 + col] = (_Float16)fv;
    G[(size_t)r*128 + col] = (_Float16)gv;
  }
  if (lane == 0){
    int mk = mask[r];
    float t = 1.f + 0.5f*explore[r] - 0.5f*exploit[r];
    t = fminf(fmaxf(t, 0.5f), 2.f);
    if (mk) t = 1.f;
    a1L[r] = 0.125f/t * L2E;
  }
}

// ---------------- fused QKV GEMM: X(8192x1024) @ WQKV(3072x1024)^T, f16 out ----------------
// seg 0 -> Q [row][1024], seg 1 -> K, seg 2 -> V transposed per-head Vt[b][h][d][s].
__global__ __launch_bounds__(256) void gemm_qkv_k(
    const short* __restrict__ A, const short* __restrict__ Wqkv,
    short* __restrict__ Q, short* __restrict__ K, short* __restrict__ Vt,
    const float* __restrict__ bq, const float* __restrict__ bk, const float* __restrict__ bv)
{
  __shared__ short As[128*32];
  __shared__ short Bs[128*32];
  __shared__ short Ct[128*136];
  const int tid = threadIdx.x;
  const int wv = tid>>6, lane = tid&63, quad = lane>>4, l16 = lane&15;
  const int m0 = blockIdx.y*128, n0g = blockIdx.x*128;
  const int seg = n0g >> 10, nloc = n0g & 1023;
  const int wm = (wv>>1)*64, wn = (wv&1)*64;
  const int rowL = tid>>2, colL = (tid&3)*8;
  fx4 acc[4][4] = {};
  for (int k0=0; k0<En; k0+=32){
    __syncthreads();
    async16(A    + (size_t)(m0+rowL)*En     + k0 + colL, &As[tid*8]);
    async16(A    + (size_t)(m0+64+rowL)*En  + k0 + colL, &As[2048 + tid*8]);
    async16(Wqkv + (size_t)(n0g+rowL)*En    + k0 + colL, &Bs[tid*8]);
    async16(Wqkv + (size_t)(n0g+64+rowL)*En + k0 + colL, &Bs[2048 + tid*8]);
    __syncthreads();
    short8 af[4], bfr[4];
    #pragma unroll
    for (int mi=0; mi<4; mi++) af[mi]  = *(const short8*)&As[(wm+mi*16+l16)*32 + quad*8];
    #pragma unroll
    for (int ni=0; ni<4; ni++) bfr[ni] = *(const short8*)&Bs[(wn+ni*16+l16)*32 + quad*8];
    #pragma unroll
    for (int mi=0; mi<4; mi++)
      #pragma unroll
      for (int ni=0; ni<4; ni++)
        acc[mi][ni] = mfma_bf(af[mi], bfr[ni], acc[mi][ni]);
  }
  const float* biasv = (seg == 0) ? bq : (seg == 1) ? bk : bv;
  if (seg < 2){
    short* C = seg ? K : Q;
    #pragma unroll
    for (int mi=0; mi<4; mi++)
      #pragma unroll
      for (int ni=0; ni<4; ni++){
        int col = nloc + wn + ni*16 + l16;
        float b0 = biasv[col];
        #pragma unroll
        for (int rg=0; rg<4; rg++){
          int row = m0 + wm + mi*16 + quad*4 + rg;
          C[(size_t)row*En + col] = f2h(acc[mi][ni][rg] + b0);
        }
      }
  } else {
    // stage transposed tile in LDS, then coalesced store to Vt[b][h][d][s]
    #pragma unroll
    for (int mi=0; mi<4; mi++)
      #pragma unroll
      for (int ni=0; ni<4; ni++){
        int lcol = wn + ni*16 + l16;
        int lrow = wm + mi*16 + quad*4;
        float b0 = biasv[nloc + lcol];
        short4v pk;
        #pragma unroll
        for (int rg=0; rg<4; rg++) pk[rg] = f2h(acc[mi][ni][rg] + b0);
        *(short4v*)&Ct[lcol*136 + lrow] = pk;
      }
    __syncthreads();
    int sl = (tid&15)*8;
    int bb = m0 >> 11, s0 = m0 & 2047;
    #pragma unroll
    for (int e8=0; e8<8; e8++){
      int e_l = e8*16 + (tid>>4);
      fx4 val = *(const fx4*)&Ct[e_l*136 + sl];
      int e_g = nloc + e_l;
      size_t dst = ((size_t)(bb*Hn + (e_g>>6))*64 + (e_g&63))*Sn + s0 + sl;
      *(fx4*)&Vt[dst] = val;
    }
  }
}

// ---------------- NT GEMM (bias matrix + output projection) ----------------
// FMT: 0 = bf16 inputs, 1 = f16 inputs.
// EPI 1: f32 out +biasv +rowmask(q)-zero.
// EPI 3: bias matrix -> btf f16 in [b][s/8][q][8] blocks; btf = v*8*a1L[q] - 8*log2e;
//        masked s (rowmask) -> -inf.  biasv = a1L array.
template<int EPI, int FMT>
__global__ __launch_bounds__(256) void gemm_nt_k(
    const short* __restrict__ A, const short* __restrict__ Bm, void* __restrict__ C,
    int Kd, int lda, int ldb, int ldc,
    long sA, long sB, long sC,
    const float* __restrict__ biasv, const int* __restrict__ rowmask)
{
  __shared__ short As[128*32];
  __shared__ short Bs[128*32];
  const short* Ab = A + (size_t)blockIdx.z*sA;
  const short* Bb = Bm + (size_t)blockIdx.z*sB;
  const int tid = threadIdx.x;
  const int wv = tid>>6, lane = tid&63, quad = lane>>4, l16 = lane&15;
  const int m0 = blockIdx.y*128, n0 = blockIdx.x*128;
  const int wm = (wv>>1)*64, wn = (wv&1)*64;
  const int rowL = tid>>2, colL = (tid&3)*8;
  fx4 acc[4][4] = {};
  for (int k0=0; k0<Kd; k0+=32){
    __syncthreads();
    async16(Ab + (size_t)(m0+rowL)*lda    + k0 + colL, &As[tid*8]);
    async16(Ab + (size_t)(m0+64+rowL)*lda + k0 + colL, &As[2048 + tid*8]);
    async16(Bb + (size_t)(n0+rowL)*ldb    + k0 + colL, &Bs[tid*8]);
    async16(Bb + (size_t)(n0+64+rowL)*ldb + k0 + colL, &Bs[2048 + tid*8]);
    __syncthreads();
    short8 af[4], bfr[4];
    #pragma unroll
    for (int mi=0; mi<4; mi++) af[mi]  = *(const short8*)&As[(wm+mi*16+l16)*32 + quad*8];
    #pragma unroll
    for (int ni=0; ni<4; ni++) bfr[ni] = *(const short8*)&Bs[(wn+ni*16+l16)*32 + quad*8];
    #pragma unroll
    for (int mi=0; mi<4; mi++)
      #pragma unroll
      for (int ni=0; ni<4; ni++){
        if constexpr (FMT == 1) acc[mi][ni] = mfma_h(af[mi], bfr[ni], acc[mi][ni]);
        else                    acc[mi][ni] = mfma_bf(af[mi], bfr[ni], acc[mi][ni]);
      }
  }
  if constexpr (EPI == 1){
    #pragma unroll
    for (int mi=0; mi<4; mi++)
      #pragma unroll
      for (int ni=0; ni<4; ni++)
        #pragma unroll
        for (int rg=0; rg<4; rg++){
          int row = m0 + wm + mi*16 + quad*4 + rg;   // C/D: row=quad*4+reg, col=lane&15 (m89)
          int col = n0 + wn + ni*16 + l16;
          float v = acc[mi][ni][rg] + biasv[col];
          if (rowmask[row]) v = 0.f;
          ((float*)C)[(size_t)row*ldc + col] = v;
        }
  } else { // EPI == 3
    _Float16* bQ = (_Float16*)C + (size_t)blockIdx.z*sC;
    #pragma unroll
    for (int mi=0; mi<4; mi++)
      #pragma unroll
      for (int ni=0; ni<4; ni++){
        int col = n0 + wn + ni*16 + l16;          // q
        int rowb = m0 + wm + mi*16 + quad*4;      // s base (≡0 mod 4)
        float s8 = 8.f * biasv[blockIdx.z*Sn + col];
        short4v pk;
        #pragma unroll
        for (int rg=0; rg<4; rg++){
          int s = rowb + rg;
          short hv;
          if (rowmask[blockIdx.z*Sn + s]) hv = (short)0xFC00;   // -inf f16
          else hv = f2h(acc[mi][ni][rg]*s8 - SH8L);
          pk[rg] = hv;
        }
        *(short4v*)&bQ[((size_t)(rowb>>3)*Sn + col)*8 + (rowb&7)] = pk;
      }
  }
}

// ---------------- flash attention v5 (all f16, exchange-free) ----------------
// 128q block, 32q/wave, S^T via 32x32x16 f16 (A=K, B=Q), lane col = q fixed.
// K rows stored in LDS with s-bits 2<->3 swapped => S^T C-row set per lane ==
// PV B-operand k-set: pfr[j] = p[c2*8+j], no cross-lane exchange at all.
// bias btf f16 in [b][s/8][q][8] blocks: one half8 load per chunk, coalesced.
// p = exp2(fma(sa, a1L, btf)) — 1 fma + 1 native exp2 per element.
__global__ __launch_bounds__(256, 4) void flash5_k(
    const short* __restrict__ Qg, const short* __restrict__ Kg, const short* __restrict__ Vtg,
    const _Float16* __restrict__ biasB, const float* __restrict__ a1Lv,
    short* __restrict__ AO)
{
  __shared__ short smem[2][2][64*64];   // [buf][K/Vt][tile] = 32 KB
  const int tid = threadIdx.x, wv = tid>>6, lane = tid&63;
  const int l32 = lane&31, hi = lane>>5;
  const int q0 = blockIdx.x*128;
  const int b = blockIdx.y >> 4, h = blockIdx.y & 15;
  const short* Qb  = Qg  + (size_t)b*Sn*En + h*64;
  const short* Kb  = Kg  + (size_t)b*Sn*En + h*64;
  const short* Vtb = Vtg + (size_t)(b*Hn + h)*64*Sn;
  const _Float16* bB = biasB + (size_t)b*Sn*Sn;   // [s/8][q][8]
  const int q = q0 + wv*32 + l32;
  const float a1L = a1Lv[b*Sn + q];

  auto issue = [&](int kt, int buf){
    #pragma unroll
    for (int rnd=0; rnd<2; rnd++){
      int idx = rnd*256 + tid;
      int r = idx>>3, c = (idx&7) ^ (r&7);              // XOR col swizzle (global side)
      int kr = (r & 51) | ((r&4)<<1) | ((r&8)>>1);      // swap s-bits 2<->3
      async16(Kb  + (size_t)(kt + kr)*En + c*8, &smem[buf][0][idx*8]);
      async16(Vtb + (size_t)r*Sn + kt + c*8,    &smem[buf][1][idx*8]);
    }
  };
  issue(0, 0);

  // Q B-frags: B[n=q][k = c*16 + hi*8 + j]
  short8 qf[4];
  #pragma unroll
  for (int c=0; c<4; c++)
    qf[c] = *(const short8*)(Qb + (size_t)q*En + c*16 + hi*8);

  fx16 o0 = {}, o1 = {};
  float psum = 0.f;

  for (int T=0; T<32; T++){
    const int kt = T*64, buf = T&1;
    __syncthreads();                      // tile T resident; buf^1 free
    if (T < 31) issue(kt+64, buf^1);

    #pragma unroll
    for (int t=0; t<2; t++){              // s-strip of 32
      // bias for both chunks (coalesced half8 loads; issue early)
      half8 bch[2];
      #pragma unroll
      for (int c2=0; c2<2; c2++){
        int sb = (kt + t*32 + c2*16 + hi*8) >> 3;
        bch[c2] = *(const half8*)&bB[((size_t)sb*Sn + q)*8];
      }
      int m = t*32 + l32;
      fx16 sa = {};
      #pragma unroll
      for (int c=0; c<4; c++){
        int g = (c*2 + hi) ^ (m&7);
        short8 ka = *(const short8*)&smem[buf][0][m*64 + g*8];
        sa = mfma32h(ka, qf[c], sa);
      }
      #pragma unroll
      for (int c2=0; c2<2; c2++){
        float p[8];
        #pragma unroll
        for (int j=0; j<8; j++){
          p[j] = __builtin_amdgcn_exp2f(fmaf(sa[c2*8 + j], a1L, (float)bch[c2][j]));
          psum += p[j];
        }
        ix4 fr = { __builtin_bit_cast(int, __builtin_amdgcn_cvt_pkrtz(p[0], p[1])),
                   __builtin_bit_cast(int, __builtin_amdgcn_cvt_pkrtz(p[2], p[3])),
                   __builtin_bit_cast(int, __builtin_amdgcn_cvt_pkrtz(p[4], p[5])),
                   __builtin_bit_cast(int, __builtin_amdgcn_cvt_pkrtz(p[6], p[7])) };
        short8 pfr = __builtin_bit_cast(short8, fr);
        int sc = t*2 + c2;
        #pragma unroll
        for (int ds=0; ds<2; ds++){
          int rv = ds*32 + l32;
          int gv = (sc*2 + hi) ^ (rv&7);
          short8 va = *(const short8*)&smem[buf][1][rv*64 + gv*8];
          if (ds == 0) o0 = mfma32h(va, pfr, o0);
          else         o1 = mfma32h(va, pfr, o1);
        }
      }
    }
  }

  psum += __shfl_xor(psum, 32, 64);
  float linv = 1.f/fmaxf(psum, 1e-30f);

  // epilogue: stage o^T -> LDS [q][d] (stride 72), then coalesced b128 stores
  __syncthreads();
  short* stage = &smem[0][0][0] + wv*2304;   // 32*72 shorts per wave
  #pragma unroll
  for (int ds=0; ds<2; ds++){
    const fx16& o = ds ? o1 : o0;
    #pragma unroll
    for (int rq=0; rq<4; rq++){
      int d0 = ds*32 + rq*8 + hi*4;
      short4v pk;
      #pragma unroll
      for (int j=0; j<4; j++) pk[j] = f2h(o[rq*4 + j]*linv);
      *(short4v*)&stage[l32*72 + d0] = pk;
    }
  }
  short* AOb = AO + (size_t)b*Sn*En + h*64;
  #pragma unroll
  for (int rnd=0; rnd<4; rnd++){
    int idx = rnd*64 + lane;
    int r = idx>>3, ch = idx&7;
    fx4 val = *(const fx4*)&stage[r*72 + ch*8];
    *(fx4*)(AOb + (size_t)(q0 + wv*32 + r)*En + ch*8) = val;
  }
}

extern "C" void kernel_launch(void* const* d_in, const int* in_sizes, int n_in,
                              void* d_out, int out_size, void* d_ws, size_t ws_size,
                              hipStream_t stream)
{
  const float* his     = (const float*)d_in[0];
  const int*   mask    = (const int*)  d_in[1];
  const float* mu      = (const float*)d_in[2];
  const float* sigma   = (const float*)d_in[3];
  const float* assign  = (const float*)d_in[4];
  const float* explore = (const float*)d_in[5];
  const float* exploit = (const float*)d_in[6];
  const float* Wq = (const float*)d_in[7];  const float* bq = (const float*)d_in[8];
  const float* Wk = (const float*)d_in[9];  const float* bk = (const float*)d_in[10];
  const float* Wv = (const float*)d_in[11]; const float* bv = (const float*)d_in[12];
  const float* Wo = (const float*)d_in[13]; const float* bo = (const float*)d_in[14];

  char* w = (char*)d_ws;
  size_t off = 0;
  auto alloc = [&](size_t bytes){ void* p = w + off; off += (bytes + 255) & ~(size_t)255; return p; };
  short*     Xb    = (short*)alloc((size_t)BSn*En*2);
  short*     WQKV  = (short*)alloc((size_t)3*En*En*2);
  short*     Wof   = (short*)alloc((size_t)En*En*2);
  short*     Qb    = (short*)alloc((size_t)BSn*En*2);
  short*     Kb    = (short*)alloc((size_t)BSn*En*2);
  short*     Vtg   = (short*)alloc((size_t)BSn*En*2);
  short*     AO    = (short*)alloc((size_t)BSn*En*2);
  _Float16*  F     = (_Float16*)alloc((size_t)BSn*128*2);
  _Float16*  G     = (_Float16*)alloc((size_t)BSn*128*2);
  _Float16*  biasT = (_Float16*)alloc((size_t)Bn*Sn*Sn*2);
  float*     a1Lp  = (float*)alloc((size_t)BSn*4);
  (void)ws_size; (void)in_sizes; (void)n_in; (void)out_size;

  cast_bf16_k<<<(BSn*En/4 + 255)/256, 256, 0, stream>>>(his, Xb, BSn*En/4);
  cast_bf16_k<<<(En*En/4 + 255)/256, 256, 0, stream>>>(Wq, WQKV,            En*En/4);
  cast_bf16_k<<<(En*En/4 + 255)/256, 256, 0, stream>>>(Wk, WQKV + En*En,    En*En/4);
  cast_bf16_k<<<(En*En/4 + 255)/256, 256, 0, stream>>>(Wv, WQKV + 2*En*En,  En*En/4);
  cast_f16_k <<<(En*En/4 + 255)/256, 256, 0, stream>>>(Wo, Wof, En*En/4);
  prep_rows_k<<<BSn, 64, 0, stream>>>(mu, sigma, assign, explore, exploit, mask, F, G, a1Lp);
  // fused Q/K/V projection, f16 out (V transposed per-head)
  gemm_qkv_k<<<dim3(3*En/128, BSn/128), 256, 0, stream>>>(Xb, WQKV, Qb, Kb, Vtg, bq, bk, bv);
  // bias: btf[b][s/8][q][8] = (G[b]@F[b]^T)*8*a1L[q] - 8log2e; masked s -> -inf
  gemm_nt_k<3,1><<<dim3(Sn/128, Sn/128, Bn), 256, 0, stream>>>(
      (const short*)G, (const short*)F, biasT, 128, 128, 128, Sn,
      (long)Sn*128, (long)Sn*128, (long)Sn*Sn, a1Lp, mask);
  flash5_k<<<dim3(Sn/128, Bn*Hn), 256, 0, stream>>>(Qb, Kb, Vtg, biasT, a1Lp, AO);
  gemm_nt_k<1,1><<<dim3(En/128, BSn/128, 1), 256, 0, stream>>>(AO, Wof, d_out, En, En, En, En, 0,0,0, bo, mask);
}

// Round 8
// 327.499 us; speedup vs baseline: 1.6072x; 1.0430x over previous
//
#include <hip/hip_runtime.h>
#include <hip/hip_bf16.h>
#include <stdint.h>
#include <stddef.h>

#define Bn 4
#define Sn 2048
#define En 1024
#define Hn 16
#define DIn 64
#define BSn (Bn*Sn)   // 8192
#define L2E 1.44269504089f
#define SH8L 11.5415603271f   // 8*log2(e)

typedef __attribute__((ext_vector_type(8))) short short8;
typedef __attribute__((ext_vector_type(4))) short short4v;
typedef __attribute__((ext_vector_type(4))) float fx4;
typedef __attribute__((ext_vector_type(16))) float fx16;
typedef __attribute__((ext_vector_type(8))) _Float16 half8;
typedef __attribute__((ext_vector_type(2))) __fp16 fp16x2;
typedef __attribute__((ext_vector_type(4))) int ix4;

__device__ __forceinline__ short f2bf(float f){
  union U { __hip_bfloat16 h; short s; } u; u.h = __float2bfloat16(f); return u.s;
}
__device__ __forceinline__ short f2h(float f){
  _Float16 h = (_Float16)f; return __builtin_bit_cast(short, h);
}

__device__ __forceinline__ void async16(const void* g, void* l){
  __builtin_amdgcn_global_load_lds((const __attribute__((address_space(1))) unsigned int*)g,
                                   (__attribute__((address_space(3))) unsigned int*)l, 16, 0, 0);
}

__device__ __forceinline__ fx4 mfma_bf(short8 a, short8 b, fx4 c){
  return __builtin_amdgcn_mfma_f32_16x16x32_bf16(a, b, c, 0, 0, 0);
}
__device__ __forceinline__ fx4 mfma_h(short8 a, short8 b, fx4 c){
  return __builtin_amdgcn_mfma_f32_16x16x32_f16(__builtin_bit_cast(half8, a),
                                                __builtin_bit_cast(half8, b), c, 0, 0, 0);
}
__device__ __forceinline__ fx16 mfma32h(short8 a, short8 b, fx16 c){
  return __builtin_amdgcn_mfma_f32_32x32x16_f16(__builtin_bit_cast(half8, a),
                                                __builtin_bit_cast(half8, b), c, 0, 0, 0);
}

// ---------------- cast his f32 -> bf16 ----------------
__global__ void cast_bf16_k(const float* __restrict__ in, short* __restrict__ out, int n4){
  int i = blockIdx.x*256 + threadIdx.x;
  if (i >= n4) return;
  fx4 v = ((const fx4*)in)[i];
  short4v o = { f2bf(v[0]), f2bf(v[1]), f2bf(v[2]), f2bf(v[3]) };
  ((short4v*)out)[i] = o;
}

// ---------------- merged weight cast: Wq/Wk/Wv -> bf16 WQKV, Wo -> f16 Wof ----------------
__global__ void cast_w_k(const float* __restrict__ Wq, const float* __restrict__ Wk,
                         const float* __restrict__ Wv, const float* __restrict__ Wo,
                         short* __restrict__ WQKV, short* __restrict__ Wof){
  int i = blockIdx.x*256 + threadIdx.x;     // short4v granularity, 4*En*En/4 total
  int seg = i >> 18;                        // En*En/4 = 262144
  int off = i & 262143;
  const float* src = (seg==0)?Wq:(seg==1)?Wk:(seg==2)?Wv:Wo;
  fx4 v = ((const fx4*)src)[off];
  short4v o;
  if (seg < 3) o = (short4v){ f2bf(v[0]), f2bf(v[1]), f2bf(v[2]), f2bf(v[3]) };
  else         o = (short4v){ f2h(v[0]),  f2h(v[1]),  f2h(v[2]),  f2h(v[3])  };
  if (seg < 3) ((short4v*)WQKV)[(size_t)seg*262144 + off] = o;
  else         ((short4v*)Wof)[off] = o;
}

// ---------------- per-(b,s) row prep (4 rows per block) ----------------
__global__ void prep_rows_k(const float* __restrict__ mu, const float* __restrict__ sigma,
                            const float* __restrict__ assign, const float* __restrict__ explore,
                            const float* __restrict__ exploit, const int* __restrict__ mask,
                            _Float16* __restrict__ F, _Float16* __restrict__ G,
                            float* __restrict__ a1L){
  int r = blockIdx.x*4 + (threadIdx.x>>6);
  int lane = threadIdx.x & 63;
  float muv = mu[(size_t)r*DIn + lane];
  float sgv = sigma[(size_t)r*DIn + lane];
  float sq = muv*muv, sg = sgv;
  #pragma unroll
  for (int m=32; m; m>>=1){ sq += __shfl_xor(sq,m,64); sg += __shfl_xor(sg,m,64); }
  float unc = sg*(1.f/64.f);
  #pragma unroll
  for (int cb=0; cb<128; cb+=64){
    int col = cb + lane;
    float fv, gv;
    if (col < 32){ float a = assign[(size_t)r*32 + col]; fv = 0.5f*a; gv = a; }
    else if (col < 96){ float m2 = mu[(size_t)r*DIn + (col-32)]; fv = m2*(1.f/64.f); gv = m2; }
    else if (col == 96){ fv = -sq*(1.f/128.f); gv = 1.f; }
    else if (col == 97){ fv = 1.f; gv = -(sq*(1.f/128.f) + 0.5f*unc); }
    else { fv = 0.f; gv = 0.f; }
    F[(size_t)r*128 + col] = (_Float16)fv;
    G[(size_t)r*128 + col] = (_Float16)gv;
  }
  if (lane == 0){
    int mk = mask[r];
    float t = 1.f + 0.5f*explore[r] - 0.5f*exploit[r];
    t = fminf(fmaxf(t, 0.5f), 2.f);
    if (mk) t = 1.f;
    a1L[r] = 0.125f/t * L2E;
  }
}

// ---------------- fused QKV GEMM: X(8192x1024) @ WQKV(3072x1024)^T, f16 out ----------------
__global__ __launch_bounds__(256) void gemm_qkv_k(
    const short* __restrict__ A, const short* __restrict__ Wqkv,
    short* __restrict__ Q, short* __restrict__ K, short* __restrict__ Vt,
    const float* __restrict__ bq, const float* __restrict__ bk, const float* __restrict__ bv)
{
  __shared__ short As[128*32];
  __shared__ short Bs[128*32];
  __shared__ short Ct[128*136];
  const int tid = threadIdx.x;
  const int wv = tid>>6, lane = tid&63, quad = lane>>4, l16 = lane&15;
  const int m0 = blockIdx.y*128, n0g = blockIdx.x*128;
  const int seg = n0g >> 10, nloc = n0g & 1023;
  const int wm = (wv>>1)*64, wn = (wv&1)*64;
  const int rowL = tid>>2, colL = (tid&3)*8;
  fx4 acc[4][4] = {};
  for (int k0=0; k0<En; k0+=32){
    __syncthreads();
    async16(A    + (size_t)(m0+rowL)*En     + k0 + colL, &As[tid*8]);
    async16(A    + (size_t)(m0+64+rowL)*En  + k0 + colL, &As[2048 + tid*8]);
    async16(Wqkv + (size_t)(n0g+rowL)*En    + k0 + colL, &Bs[tid*8]);
    async16(Wqkv + (size_t)(n0g+64+rowL)*En + k0 + colL, &Bs[2048 + tid*8]);
    __syncthreads();
    short8 af[4], bfr[4];
    #pragma unroll
    for (int mi=0; mi<4; mi++) af[mi]  = *(const short8*)&As[(wm+mi*16+l16)*32 + quad*8];
    #pragma unroll
    for (int ni=0; ni<4; ni++) bfr[ni] = *(const short8*)&Bs[(wn+ni*16+l16)*32 + quad*8];
    #pragma unroll
    for (int mi=0; mi<4; mi++)
      #pragma unroll
      for (int ni=0; ni<4; ni++)
        acc[mi][ni] = mfma_bf(af[mi], bfr[ni], acc[mi][ni]);
  }
  const float* biasv = (seg == 0) ? bq : (seg == 1) ? bk : bv;
  if (seg < 2){
    short* C = seg ? K : Q;
    #pragma unroll
    for (int mi=0; mi<4; mi++)
      #pragma unroll
      for (int ni=0; ni<4; ni++){
        int col = nloc + wn + ni*16 + l16;
        float b0 = biasv[col];
        #pragma unroll
        for (int rg=0; rg<4; rg++){
          int row = m0 + wm + mi*16 + quad*4 + rg;
          C[(size_t)row*En + col] = f2h(acc[mi][ni][rg] + b0);
        }
      }
  } else {
    #pragma unroll
    for (int mi=0; mi<4; mi++)
      #pragma unroll
      for (int ni=0; ni<4; ni++){
        int lcol = wn + ni*16 + l16;
        int lrow = wm + mi*16 + quad*4;
        float b0 = biasv[nloc + lcol];
        short4v pk;
        #pragma unroll
        for (int rg=0; rg<4; rg++) pk[rg] = f2h(acc[mi][ni][rg] + b0);
        *(short4v*)&Ct[lcol*136 + lrow] = pk;
      }
    __syncthreads();
    int sl = (tid&15)*8;
    int bb = m0 >> 11, s0 = m0 & 2047;
    #pragma unroll
    for (int e8=0; e8<8; e8++){
      int e_l = e8*16 + (tid>>4);
      fx4 val = *(const fx4*)&Ct[e_l*136 + sl];
      int e_g = nloc + e_l;
      size_t dst = ((size_t)(bb*Hn + (e_g>>6))*64 + (e_g&63))*Sn + s0 + sl;
      *(fx4*)&Vt[dst] = val;
    }
  }
}

// ---------------- single-stage bias GEMM: btf[b][s/8][q][8] = (G@F^T)*8*a1L[q]-SH8L ----------------
// K=128 staged entirely in LDS (XOR-swizzled), one barrier, 64 MFMAs. masked s -> -inf.
__global__ __launch_bounds__(256) void gemm_bias_k(
    const short* __restrict__ G, const short* __restrict__ F, _Float16* __restrict__ biasT,
    const float* __restrict__ a1L, const int* __restrict__ mask)
{
  __shared__ short As[128*128];   // G rows (s)
  __shared__ short Bs[128*128];   // F rows (q)
  const int tid = threadIdx.x, b = blockIdx.z;
  const int wv = tid>>6, lane = tid&63, quad = lane>>4, l16 = lane&15;
  const int m0 = blockIdx.y*128, n0 = blockIdx.x*128;
  const int wm = (wv>>1)*64, wn = (wv&1)*64;
  const short* Ab = G + ((size_t)b*Sn + m0)*128;
  const short* Bb = F + ((size_t)b*Sn + n0)*128;
  #pragma unroll
  for (int i=0; i<8; i++){
    int idx = i*256 + tid;
    int r = idx>>4, cl = idx&15, c = cl ^ (r&7);
    async16(Ab + (size_t)r*128 + c*8, &As[idx*8]);
    async16(Bb + (size_t)r*128 + c*8, &Bs[idx*8]);
  }
  __syncthreads();
  fx4 acc[4][4] = {};
  #pragma unroll
  for (int k0=0; k0<128; k0+=32){
    short8 af[4], bfr[4];
    #pragma unroll
    for (int mi=0; mi<4; mi++){
      int row = wm + mi*16 + l16, kc = (k0>>3) + quad, pc = kc ^ (row&7);
      af[mi] = *(const short8*)&As[row*128 + pc*8];
    }
    #pragma unroll
    for (int ni=0; ni<4; ni++){
      int row = wn + ni*16 + l16, kc = (k0>>3) + quad, pc = kc ^ (row&7);
      bfr[ni] = *(const short8*)&Bs[row*128 + pc*8];
    }
    #pragma unroll
    for (int mi=0; mi<4; mi++)
      #pragma unroll
      for (int ni=0; ni<4; ni++)
        acc[mi][ni] = mfma_h(af[mi], bfr[ni], acc[mi][ni]);
  }
  _Float16* bQ = biasT + (size_t)b*Sn*Sn;
  #pragma unroll
  for (int mi=0; mi<4; mi++)
    #pragma unroll
    for (int ni=0; ni<4; ni++){
      int col = n0 + wn + ni*16 + l16;          // q
      int rowb = m0 + wm + mi*16 + quad*4;      // s base
      float s8 = 8.f * a1L[b*Sn + col];
      short4v pk;
      #pragma unroll
      for (int rg=0; rg<4; rg++){
        int s = rowb + rg;
        short hv;
        if (mask[b*Sn + s]) hv = (short)0xFC00;
        else hv = f2h(acc[mi][ni][rg]*s8 - SH8L);
        pk[rg] = hv;
      }
      *(short4v*)&bQ[((size_t)(rowb>>3)*Sn + col)*8 + (rowb&7)] = pk;
    }
}

// ---------------- output projection: AO @ Wo^T + bo, f32 out, masked rows zero ----------------
__global__ __launch_bounds__(256) void gemm_out_k(
    const short* __restrict__ A, const short* __restrict__ Bm, float* __restrict__ C,
    const float* __restrict__ biasv, const int* __restrict__ rowmask)
{
  __shared__ short As[128*32];
  __shared__ short Bs[128*32];
  const int tid = threadIdx.x;
  const int wv = tid>>6, lane = tid&63, quad = lane>>4, l16 = lane&15;
  const int m0 = blockIdx.y*128, n0 = blockIdx.x*128;
  const int wm = (wv>>1)*64, wn = (wv&1)*64;
  const int rowL = tid>>2, colL = (tid&3)*8;
  fx4 acc[4][4] = {};
  for (int k0=0; k0<En; k0+=32){
    __syncthreads();
    async16(A  + (size_t)(m0+rowL)*En    + k0 + colL, &As[tid*8]);
    async16(A  + (size_t)(m0+64+rowL)*En + k0 + colL, &As[2048 + tid*8]);
    async16(Bm + (size_t)(n0+rowL)*En    + k0 + colL, &Bs[tid*8]);
    async16(Bm + (size_t)(n0+64+rowL)*En + k0 + colL, &Bs[2048 + tid*8]);
    __syncthreads();
    short8 af[4], bfr[4];
    #pragma unroll
    for (int mi=0; mi<4; mi++) af[mi]  = *(const short8*)&As[(wm+mi*16+l16)*32 + quad*8];
    #pragma unroll
    for (int ni=0; ni<4; ni++) bfr[ni] = *(const short8*)&Bs[(wn+ni*16+l16)*32 + quad*8];
    #pragma unroll
    for (int mi=0; mi<4; mi++)
      #pragma unroll
      for (int ni=0; ni<4; ni++)
        acc[mi][ni] = mfma_h(af[mi], bfr[ni], acc[mi][ni]);
  }
  #pragma unroll
  for (int mi=0; mi<4; mi++)
    #pragma unroll
    for (int ni=0; ni<4; ni++)
      #pragma unroll
      for (int rg=0; rg<4; rg++){
        int row = m0 + wm + mi*16 + quad*4 + rg;
        int col = n0 + wn + ni*16 + l16;
        float v = acc[mi][ni][rg] + biasv[col];
        if (rowmask[row]) v = 0.f;
        C[(size_t)row*En + col] = v;
      }
}

// ---------------- flash attention v6 (strength-reduced v5) ----------------
// All loop-varying global addresses are pointer-incremented; LDS offsets hoisted.
// psum via v_dot2_f32_f16 on the packed P pairs (denominator == quantized numerator).
__global__ __launch_bounds__(256, 4) void flash6_k(
    const short* __restrict__ Qg, const short* __restrict__ Kg, const short* __restrict__ Vtg,
    const _Float16* __restrict__ biasB, const float* __restrict__ a1Lv,
    short* __restrict__ AO)
{
  __shared__ short smem[2][2][64*64];   // [buf][K/Vt][tile] = 32 KB
  const int tid = threadIdx.x, wv = tid>>6, lane = tid&63;
  const int l32 = lane&31, hi = lane>>5;
  const int q0 = blockIdx.x*128;
  const int b = blockIdx.y >> 4, h = blockIdx.y & 15;
  const short* Qb  = Qg  + (size_t)b*Sn*En + h*64;
  const int q = q0 + wv*32 + l32;
  const float a1L = a1Lv[b*Sn + q];

  // thread-fixed staging coords (rnd1 = rnd0 + 32 rows; col swizzle identical)
  const int r0 = tid>>3, c0 = (tid&7) ^ (r0&7);
  const int kr0 = (r0 & 51) | ((r0&4)<<1) | ((r0&8)>>1);   // s-bits 2<->3 swap
  const short* kA = Kg  + (size_t)b*Sn*En + h*64 + (size_t)kr0*En + c0*8;
  const short* vA = Vtg + (size_t)(b*Hn + h)*64*Sn + (size_t)r0*Sn + c0*8;
  const _Float16* bP = biasB + (size_t)b*Sn*Sn + ((size_t)hi*Sn + q)*8;
  const int ld0 = tid*8;   // LDS slot (shorts), rnd1 = +2048

  auto issue = [&](int buf){
    short* base = &smem[buf][0][0];
    async16(kA,             base + ld0);
    async16(kA + 32*En,     base + 2048 + ld0);
    async16(vA,             base + 4096 + ld0);
    async16(vA + 32*Sn,     base + 4096 + 2048 + ld0);
  };
  issue(0);
  kA += 64*En; vA += 64;

  // Q B-frags: B[n=q][k = c*16 + hi*8 + j]
  short8 qf[4];
  #pragma unroll
  for (int c=0; c<4; c++)
    qf[c] = *(const short8*)(Qb + (size_t)q*En + c*16 + hi*8);

  // loop-invariant LDS read offsets (shorts), K plane / V plane
  int koff[2][4], voff[2][4];
  #pragma unroll
  for (int t=0; t<2; t++){
    int m = t*32 + l32;
    #pragma unroll
    for (int c=0; c<4; c++)
      koff[t][c] = m*64 + (((c*2 + hi) ^ (m&7))*8);
  }
  #pragma unroll
  for (int ds=0; ds<2; ds++){
    int rv = ds*32 + l32;
    #pragma unroll
    for (int sc=0; sc<4; sc++)
      voff[ds][sc] = 4096 + rv*64 + (((sc*2 + hi) ^ (rv&7))*8);
  }

  fp16x2 one2; one2[0] = (__fp16)1.0f; one2[1] = (__fp16)1.0f;
  fx16 o0 = {}, o1 = {};
  float psum = 0.f;

  for (int T=0; T<32; T++){
    __syncthreads();                      // tile T resident; other buf free
    const short* base = &smem[T&1][0][0];
    if (T < 31){ issue((T&1)^1); kA += 64*En; vA += 64; }

    #pragma unroll
    for (int t=0; t<2; t++){              // s-strip of 32
      half8 bch[2];
      #pragma unroll
      for (int c2=0; c2<2; c2++)
        bch[c2] = *(const half8*)(bP + (size_t)(t*4 + c2*2)*Sn*8);
      fx16 sa = {};
      #pragma unroll
      for (int c=0; c<4; c++){
        short8 ka = *(const short8*)(base + koff[t][c]);
        sa = mfma32h(ka, qf[c], sa);
      }
      #pragma unroll
      for (int c2=0; c2<2; c2++){
        fp16x2 pk_[4];
        #pragma unroll
        for (int jj=0; jj<4; jj++){
          float pa = __builtin_amdgcn_exp2f(fmaf(sa[c2*8 + jj*2],     a1L, (float)bch[c2][jj*2]));
          float pb = __builtin_amdgcn_exp2f(fmaf(sa[c2*8 + jj*2 + 1], a1L, (float)bch[c2][jj*2+1]));
          pk_[jj] = __builtin_amdgcn_cvt_pkrtz(pa, pb);
          psum = __builtin_amdgcn_fdot2(pk_[jj], one2, psum, false);
        }
        ix4 fr = { __builtin_bit_cast(int, pk_[0]), __builtin_bit_cast(int, pk_[1]),
                   __builtin_bit_cast(int, pk_[2]), __builtin_bit_cast(int, pk_[3]) };
        short8 pfr = __builtin_bit_cast(short8, fr);
        int sc = t*2 + c2;
        #pragma unroll
        for (int ds=0; ds<2; ds++){
          short8 va = *(const short8*)(base + voff[ds][sc]);
          if (ds == 0) o0 = mfma32h(va, pfr, o0);
          else         o1 = mfma32h(va, pfr, o1);
        }
      }
    }
    bP += (size_t)8*Sn*8;
  }

  psum += __shfl_xor(psum, 32, 64);
  float linv = 1.f/fmaxf(psum, 1e-30f);

  // epilogue: stage o^T -> LDS [q][d] (stride 72), then coalesced b128 stores
  __syncthreads();
  short* stage = &smem[0][0][0] + wv*2304;   // 32*72 shorts per wave
  #pragma unroll
  for (int ds=0; ds<2; ds++){
    const fx16& o = ds ? o1 : o0;
    #pragma unroll
    for (int rq=0; rq<4; rq++){
      int d0 = ds*32 + rq*8 + hi*4;
      short4v pk;
      #pragma unroll
      for (int j=0; j<4; j++) pk[j] = f2h(o[rq*4 + j]*linv);
      *(short4v*)&stage[l32*72 + d0] = pk;
    }
  }
  short* AOb = AO + (size_t)b*Sn*En + h*64;
  #pragma unroll
  for (int rnd=0; rnd<4; rnd++){
    int idx = rnd*64 + lane;
    int r = idx>>3, ch = idx&7;
    fx4 val = *(const fx4*)&stage[r*72 + ch*8];
    *(fx4*)(AOb + (size_t)(q0 + wv*32 + r)*En + ch*8) = val;
  }
}

extern "C" void kernel_launch(void* const* d_in, const int* in_sizes, int n_in,
                              void* d_out, int out_size, void* d_ws, size_t ws_size,
                              hipStream_t stream)
{
  const float* his     = (const float*)d_in[0];
  const int*   mask    = (const int*)  d_in[1];
  const float* mu      = (const float*)d_in[2];
  const float* sigma   = (const float*)d_in[3];
  const float* assign  = (const float*)d_in[4];
  const float* explore = (const float*)d_in[5];
  const float* exploit = (const float*)d_in[6];
  const float* Wq = (const float*)d_in[7];  const float* bq = (const float*)d_in[8];
  const float* Wk = (const float*)d_in[9];  const float* bk = (const float*)d_in[10];
  const float* Wv = (const float*)d_in[11]; const float* bv = (const float*)d_in[12];
  const float* Wo = (const float*)d_in[13]; const float* bo = (const float*)d_in[14];

  char* w = (char*)d_ws;
  size_t off = 0;
  auto alloc = [&](size_t bytes){ void* p = w + off; off += (bytes + 255) & ~(size_t)255; return p; };
  short*     Xb    = (short*)alloc((size_t)BSn*En*2);
  short*     WQKV  = (short*)alloc((size_t)3*En*En*2);
  short*     Wof   = (short*)alloc((size_t)En*En*2);
  short*     Qb    = (short*)alloc((size_t)BSn*En*2);
  short*     Kb    = (short*)alloc((size_t)BSn*En*2);
  short*     Vtg   = (short*)alloc((size_t)BSn*En*2);
  short*     AO    = (short*)alloc((size_t)BSn*En*2);
  _Float16*  F     = (_Float16*)alloc((size_t)BSn*128*2);
  _Float16*  G     = (_Float16*)alloc((size_t)BSn*128*2);
  _Float16*  biasT = (_Float16*)alloc((size_t)Bn*Sn*Sn*2);
  float*     a1Lp  = (float*)alloc((size_t)BSn*4);
  (void)ws_size; (void)in_sizes; (void)n_in; (void)out_size;

  cast_bf16_k<<<(BSn*En/4 + 255)/256, 256, 0, stream>>>(his, Xb, BSn*En/4);
  cast_w_k<<<4*En*En/4/256, 256, 0, stream>>>(Wq, Wk, Wv, Wo, WQKV, Wof);
  prep_rows_k<<<BSn/4, 256, 0, stream>>>(mu, sigma, assign, explore, exploit, mask, F, G, a1Lp);
  gemm_qkv_k<<<dim3(3*En/128, BSn/128), 256, 0, stream>>>(Xb, WQKV, Qb, Kb, Vtg, bq, bk, bv);
  gemm_bias_k<<<dim3(Sn/128, Sn/128, Bn), 256, 0, stream>>>(
      (const short*)G, (const short*)F, biasT, a1Lp, mask);
  flash6_k<<<dim3(Sn/128, Bn*Hn), 256, 0, stream>>>(Qb, Kb, Vtg, biasT, a1Lp, AO);
  gemm_out_k<<<dim3(En/128, BSn/128), 256, 0, stream>>>(AO, Wof, (float*)d_out, bo, mask);
}